// Round 10
// baseline (167.356 us; speedup 1.0000x reference)
//
#include <hip/hip_runtime.h>
#include <hip/hip_bf16.h>

typedef __attribute__((ext_vector_type(8))) short short8;
typedef __attribute__((ext_vector_type(16))) float floatx16;
typedef __attribute__((ext_vector_type(4))) float floatx4;
typedef __attribute__((ext_vector_type(4))) unsigned uintx4;

__device__ __forceinline__ short f2bf(float f) {
    unsigned u = __builtin_bit_cast(unsigned, f);
    u += 0x7fffu + ((u >> 16) & 1u);   // RNE
    return (short)(u >> 16);
}

__device__ __forceinline__ unsigned pk_bf16(float lo, float hi) {
    unsigned short a = __builtin_bit_cast(unsigned short, (__bf16)lo);
    unsigned short b = __builtin_bit_cast(unsigned short, (__bf16)hi);
    return (unsigned)a | ((unsigned)b << 16);
}

__device__ __forceinline__ void gload_lds16(const void* g, void* l) {
    __builtin_amdgcn_global_load_lds(
        (const __attribute__((address_space(1))) unsigned*)g,
        (__attribute__((address_space(3))) unsigned*)l, 16, 0, 0);
}

// ---------------------------------------------------------------------------
// f32 -> bf16 convert for x, Wq/Wk/Wv, Wo — one launch. 64-col-tile XOR
// swizzle (GEMM operand layout): chunk cc of dest row holds src chunk cc^(row&7).
__global__ __launch_bounds__(256)
void conv_all(const float* __restrict__ x, const float* __restrict__ Wq,
              const float* __restrict__ Wk, const float* __restrict__ Wv,
              const float* __restrict__ Wo, short* __restrict__ xb,
              short* __restrict__ wqkv, short* __restrict__ wob) {
    const int bid = blockIdx.x;                // 0..7167
    const float* src; short* dst; int srow, drow;
    if (bid < 2048)      { src = x;  dst = xb;  srow = bid;        drow = bid; }
    else if (bid < 5120) {
        int r = bid - 2048;
        dst = wqkv; drow = r;
        if (r < 2048)      { src = Wq; srow = r; }
        else if (r < 2560) { src = Wk; srow = r - 2048; }
        else               { src = Wv; srow = r - 2560; }
    } else               { src = Wo; dst = wob; srow = bid - 5120; drow = srow; }
    const int c = threadIdx.x;
    const int kt = c >> 3, cc = c & 7;
    const float* s = src + (size_t)srow * 2048 + kt * 64 + (cc ^ (drow & 7)) * 8;
    float4 v0 = *(const float4*)s;
    float4 v1 = *(const float4*)(s + 4);
    short8 o = { f2bf(v0.x), f2bf(v0.y), f2bf(v0.z), f2bf(v0.w),
                 f2bf(v1.x), f2bf(v1.y), f2bf(v1.z), f2bf(v1.w) };
    *(short8*)(dst + (size_t)drow * 2048 + kt * 64 + cc * 8) = o;
}

// ---------------------------------------------------------------------------
// 8-wave double-buffered bf16 GEMM (round-8 structure; kb/vt now PLAIN layouts).
template<int BN, int EPI>
__global__ __launch_bounds__(512, 4)
void gemm8(const short* __restrict__ A, const short* __restrict__ Bw,
           short* __restrict__ qb, short* __restrict__ kb, short* __restrict__ vt,
           float* __restrict__ fout, const float* __restrict__ bias) {
    constexpr int K = 2048;
    constexpr int NN = BN / 32;
    constexpr int ACH = 128 * 8;
    constexpr int NCH = (128 + BN) * 8;
    constexpr int NIT = K / 64;
    __shared__ short sm[2][(128 + BN) * 64];

    const int t = threadIdx.x, lane = t & 63, w = t >> 6;
    const int wm = w & 3, wn = w >> 2;
    const int l15 = lane & 15, lh = lane >> 4;
    const int bn = blockIdx.x, bm = blockIdx.y;
    const int ra0 = bm * 128;
    const short* Bbase = Bw + (size_t)bn * BN * K;

    floatx4 acc[2][NN] = {};

    auto stage = [&](int buf, int k0) {
        short* base = &sm[buf][0];
        #pragma unroll
        for (int i = 0; i < NCH / 512; ++i) {
            int c = i * 512 + t;
            if (c < ACH) {
                int row = c >> 3, cc = c & 7;
                gload_lds16(A + (size_t)(ra0 + row) * K + k0 + cc * 8, base + c * 8);
            } else {
                int c2 = c - ACH;
                int row = c2 >> 3, cc = c2 & 7;
                gload_lds16(Bbase + (size_t)row * K + k0 + cc * 8, base + (ACH + c2) * 8);
            }
        }
    };

    stage(0, 0);
    #pragma unroll 1
    for (int it = 0; it < NIT; ++it) {
        __syncthreads();                       // slab `it` ready
        if (it + 1 < NIT) stage((it + 1) & 1, (it + 1) * 64);
        const short* As = &sm[it & 1][0];
        const short* Bs = As + 128 * 64;
        #pragma unroll
        for (int kf = 0; kf < 2; ++kf) {
            short8 a[2], b[NN];
            #pragma unroll
            for (int m = 0; m < 2; ++m) {
                int arow = wm * 32 + m * 16 + l15;
                a[m] = *(const short8*)(As + arow * 64 + (((kf * 4 + lh) ^ (arow & 7)) << 3));
            }
            #pragma unroll
            for (int n = 0; n < NN; ++n) {
                int brow = wn * (BN / 2) + n * 16 + l15;
                b[n] = *(const short8*)(Bs + brow * 64 + (((kf * 4 + lh) ^ (brow & 7)) << 3));
            }
            #pragma unroll
            for (int m = 0; m < 2; ++m)
                #pragma unroll
                for (int n = 0; n < NN; ++n)
                    acc[m][n] = __builtin_amdgcn_mfma_f32_16x16x32_bf16(a[m], b[n], acc[m][n], 0, 0, 0);
        }
    }

    #pragma unroll
    for (int m = 0; m < 2; ++m) {
        #pragma unroll
        for (int n = 0; n < NN; ++n) {
            #pragma unroll
            for (int r = 0; r < 4; ++r) {
                int row = ra0 + wm * 32 + m * 16 + lh * 4 + r;
                int col = bn * BN + wn * (BN / 2) + n * 16 + l15;
                float v = acc[m][n][r];
                if constexpr (EPI == 1) {
                    fout[(size_t)row * 2048 + col] = v + bias[col];
                } else {
                    if (col < 2048) {
                        qb[(size_t)row * 2048 + col] = f2bf(v * 0.18033688011112042f);
                    } else if (col < 2560) {
                        kb[(size_t)row * 512 + (col - 2048)] = f2bf(v);   // plain
                    } else {
                        vt[(size_t)(col - 2560) * 2048 + row] = f2bf(v);  // plain V^T
                    }
                }
            }
        }
    }
}

// ---------------------------------------------------------------------------
// Causal GQA attention — barrier-free main loop, K/V fragments direct from
// global (L2-resident). Pair {qtA=pairi, qtB=31-pairi}: 66 unit-tiles
// (2 strips x [A-tiles 0..qtA, B-tiles 0..qtB]) split evenly over 8 waves
// (uniform 8-9 unit chains). Each wave flushes <=1 mid-chain partial
// (bf16-packed) at its A->B boundary; ONE __syncthreads; 4 owner waves merge
// (slot membership closed-form from qtA) and write out.
__global__ __launch_bounds__(512, 4)
void attn_fwd(const short* __restrict__ qb, const short* __restrict__ kb,
              const short* __restrict__ vt, short* __restrict__ ob) {
    // slots [0..7]: per-wave last segment; [8+seq]: crossing wave's A-partial.
    __shared__ __align__(16) unsigned slots[10][64][20];  // 16 pk-acc + m + l (+pad)

    const int t = threadIdx.x, lane = t & 63, w = t >> 6;
    const int l31 = lane & 31, hi = lane >> 5;
    const int bid = blockIdx.x;
    const int pairi = bid >> 5;            // 0..15
    const int hq = bid & 31;               // bid%8 == head%8 -> 4 heads per XCD
    const int hk = hq >> 2;
    const int qtA = pairi, qtB = 31 - pairi;
    const int nA = qtA + 1;

    const int start = (w * 66) >> 3;       // 0,8,16,24,33,41,49,57
    const int end = ((w + 1) * 66) >> 3;

    float m = -3e38f, l = 0.f;
    floatx16 acc[2] = {};
    short8 qf[4];
    int rg = 0;

    auto save_part = [&](unsigned* mb) {
        #pragma unroll
        for (int n = 0; n < 2; ++n)
            #pragma unroll
            for (int r = 0; r < 16; r += 2)
                mb[n * 8 + (r >> 1)] = pk_bf16(acc[n][r], acc[n][r + 1]);
        mb[16] = __builtin_bit_cast(unsigned, m);
        mb[17] = __builtin_bit_cast(unsigned, l);
    };
    auto merge_part = [&](const unsigned* mb) {
        float m1 = __builtin_bit_cast(float, mb[16]);
        float l1 = __builtin_bit_cast(float, mb[17]);
        float M = fmaxf(m, m1);
        float sf0 = __builtin_amdgcn_exp2f(m - M);
        float sf1 = __builtin_amdgcn_exp2f(m1 - M);
        l = sf0 * l + sf1 * l1;
        #pragma unroll
        for (int n = 0; n < 2; ++n)
            #pragma unroll
            for (int r = 0; r < 16; r += 2) {
                unsigned pk = mb[n * 8 + (r >> 1)];
                float lo = __builtin_bit_cast(float, pk << 16);
                float hv = __builtin_bit_cast(float, pk & 0xffff0000u);
                acc[n][r]     = sf0 * acc[n][r]     + sf1 * lo;
                acc[n][r + 1] = sf0 * acc[n][r + 1] + sf1 * hv;
            }
        m = M;
    };

    // ---- main loop: no barriers, no LDS
    int prev_tag = -1;
    #pragma unroll 1
    for (int u = start; u < end; ++u) {
        const int seq = (u >= 33) ? 1 : 0;
        const int v = u - (seq ? 33 : 0);
        const int isB = (v > qtA) ? 1 : 0;
        const int tile = isB ? qtB : qtA;
        const int kt = isB ? v - nA : v;
        const int tag = (seq << 1) | isB;
        if (tag != prev_tag) {
            if (prev_tag >= 0) {               // A->B crossing: flush A-partial
                save_part(&slots[8 + seq][lane][0]);
                m = -3e38f; l = 0.f;
                acc[0] = (floatx16){}; acc[1] = (floatx16){};
            }
            prev_tag = tag;
            rg = tile * 64 + seq * 32 + l31;
            const short* qrow = qb + (size_t)rg * 2048 + hq * 64;
            #pragma unroll
            for (int kk = 0; kk < 4; ++kk)
                qf[kk] = *(const short8*)(qrow + kk * 16 + hi * 8);
        }

        // ---- K fragments direct from global; S^T = K . Q^T
        const short* kbase = kb + (size_t)(kt * 64 + l31) * 512 + hk * 64 + hi * 8;
        short8 kf0[4], kf1[4];
        #pragma unroll
        for (int kk = 0; kk < 4; ++kk) kf0[kk] = *(const short8*)(kbase + kk * 16);
        #pragma unroll
        for (int kk = 0; kk < 4; ++kk) kf1[kk] = *(const short8*)(kbase + 32 * 512 + kk * 16);
        floatx16 sT[2];
        {
            floatx16 s0 = {}, s1 = {};
            __builtin_amdgcn_s_setprio(1);
            #pragma unroll
            for (int kk = 0; kk < 4; ++kk) {
                s0 = __builtin_amdgcn_mfma_f32_32x32x16_bf16(kf0[kk], qf[kk], s0, 0, 0, 0);
                s1 = __builtin_amdgcn_mfma_f32_32x32x16_bf16(kf1[kk], qf[kk], s1, 0, 0, 0);
            }
            __builtin_amdgcn_s_setprio(0);
            sT[0] = s0; sT[1] = s1;
        }

        // ---- causal mask (diagonal tile only)
        if (kt == tile) {
            #pragma unroll
            for (int ib = 0; ib < 2; ++ib)
                #pragma unroll
                for (int r = 0; r < 16; ++r) {
                    int jg = kt * 64 + ib * 32 + (r & 3) + 8 * (r >> 2) + 4 * hi;
                    if (jg > rg) sT[ib][r] = -3e38f;
                }
        }

        // ---- row max (in-lane tree + 1 cross-half exchange)
        float vr[16];
        #pragma unroll
        for (int r = 0; r < 16; ++r) vr[r] = fmaxf(sT[0][r], sT[1][r]);
        #pragma unroll
        for (int st = 8; st >= 1; st >>= 1)
            #pragma unroll
            for (int r = 0; r < 8; ++r)
                if (r < st) vr[r] = fmaxf(vr[r], vr[r + st]);
        float tm = fmaxf(vr[0], __shfl_xor(vr[0], 32));

        // ---- defer-max
        if (!__all(tm <= m + 8.0f)) {
            float mn = fmaxf(m, tm);
            float sf = __builtin_amdgcn_exp2f(m - mn);
            m = mn;
            l *= sf;
            #pragma unroll
            for (int n = 0; n < 2; ++n)
                #pragma unroll
                for (int r = 0; r < 16; ++r) acc[n][r] *= sf;
        }

        // ---- V fragments issued here: L2 latency hides under exp2/pack VALU
        const short* vbase = vt + (size_t)(hk * 64 + l31) * 2048 + kt * 64 + hi * 8;
        short8 vf0[4], vf1[4];
        #pragma unroll
        for (int kk = 0; kk < 4; ++kk) vf0[kk] = *(const short8*)(vbase + kk * 16);
        #pragma unroll
        for (int kk = 0; kk < 4; ++kk) vf1[kk] = *(const short8*)(vbase + (size_t)32 * 2048 + kk * 16);

        // ---- p = exp2(s - m), row sum
        float sv[16];
        #pragma unroll
        for (int ib = 0; ib < 2; ++ib)
            #pragma unroll
            for (int r = 0; r < 16; ++r)
                sT[ib][r] = __builtin_amdgcn_exp2f(sT[ib][r] - m);
        #pragma unroll
        for (int r = 0; r < 16; ++r) sv[r] = sT[0][r] + sT[1][r];
        #pragma unroll
        for (int st = 8; st >= 1; st >>= 1)
            #pragma unroll
            for (int r = 0; r < 8; ++r)
                if (r < st) sv[r] += sv[r + st];
        l += sv[0] + __shfl_xor(sv[0], 32);

        // ---- P^T -> B-fragments (cvt_pk + cross-half exchange), then PV
        #pragma unroll
        for (int ib = 0; ib < 2; ++ib) {
            unsigned Qd[8], Pd[8];
            #pragma unroll
            for (int c = 0; c < 8; ++c)
                Qd[c] = pk_bf16(sT[ib][2 * c], sT[ib][2 * c + 1]);
            #pragma unroll
            for (int c = 0; c < 8; ++c)
                Pd[c] = __shfl_xor(Qd[c], 32);
            __builtin_amdgcn_s_setprio(1);
            #pragma unroll
            for (int b = 0; b < 2; ++b) {
                uintx4 j;
                if (b == 0) {
                    j.x = hi ? Pd[2] : Qd[0];
                    j.y = hi ? Pd[3] : Qd[1];
                    j.z = hi ? Qd[2] : Pd[0];
                    j.w = hi ? Qd[3] : Pd[1];
                } else {
                    j.x = hi ? Pd[6] : Qd[4];
                    j.y = hi ? Pd[7] : Qd[5];
                    j.z = hi ? Qd[6] : Pd[4];
                    j.w = hi ? Qd[7] : Pd[5];
                }
                short8 pf = __builtin_bit_cast(short8, j);
                const int kk = ib * 2 + b;
                acc[0] = __builtin_amdgcn_mfma_f32_32x32x16_bf16(vf0[kk], pf, acc[0], 0, 0, 0);
                acc[1] = __builtin_amdgcn_mfma_f32_32x32x16_bf16(vf1[kk], pf, acc[1], 0, 0, 0);
            }
            __builtin_amdgcn_s_setprio(0);
        }
    }

    // ---- flush last segment; single barrier; owners merge + write out
    save_part(&slots[w][lane][0]);
    __syncthreads();

    int myTag = (w == 0) ? 0 : (w == 3) ? 1 : (w == 4) ? 2 : (w == 7) ? 3 : -1;
    if (myTag >= 0) {
        m = -3e38f; l = 0.f;
        acc[0] = (floatx16){}; acc[1] = (floatx16){};
        #pragma unroll
        for (int w8 = 0; w8 < 8; ++w8) {
            int uu = ((w8 + 1) * 66) / 8 - 1;          // last unit of wave w8
            int sq = (uu >= 33) ? 1 : 0;
            int vv = uu - (sq ? 33 : 0);
            int tg = (sq << 1) | ((vv > qtA) ? 1 : 0);
            if (tg == myTag) merge_part(&slots[w8][lane][0]);
        }
        if (!(myTag & 1) && (nA & 7) && nA < 16)       // crossing A-partial exists
            merge_part(&slots[8 + (myTag >> 1)][lane][0]);

        const int s = myTag >> 1, isB = myTag & 1;
        const int rgw = (isB ? qtB : qtA) * 64 + s * 32 + l31;
        const float linv = 1.0f / l;
        const int sw8 = rgw & 7;
        #pragma unroll
        for (int n = 0; n < 2; ++n) {
            #pragma unroll
            for (int g = 0; g < 4; ++g) {
                #pragma unroll
                for (int e = 0; e < 4; e += 2) {
                    int r = 4 * g + e;
                    unsigned pkv = pk_bf16(acc[n][r] * linv, acc[n][r + 1] * linv);
                    int d = 32 * n + e + 8 * g + 4 * hi;
                    int col = hq * 64 + d;
                    int cp = ((col >> 3) & 7) ^ sw8;   // GEMM-A 64-col swizzle for O-proj
                    *(unsigned*)(ob + (size_t)rgw * 2048 + (col & ~63) + (cp << 3) + (col & 7)) = pkv;
                }
            }
        }
    }
}

// ---------------------------------------------------------------------------
extern "C" void kernel_launch(void* const* d_in, const int* in_sizes, int n_in,
                              void* d_out, int out_size, void* d_ws, size_t ws_size,
                              hipStream_t stream) {
    const float* x  = (const float*)d_in[0];
    const float* Wq = (const float*)d_in[1];
    const float* Wk = (const float*)d_in[2];
    const float* Wv = (const float*)d_in[3];
    const float* Wo = (const float*)d_in[4];
    const float* bo = (const float*)d_in[5];

    char* ws = (char*)d_ws;
    short* xb   = (short*)ws;                            // 8 MiB (reused as ob)
    short* wqkv = (short*)(ws + ((size_t)8  << 20));     // 12 MiB
    short* qb   = (short*)(ws + ((size_t)20 << 20));     // 8 MiB
    short* kb   = (short*)(ws + ((size_t)28 << 20));     // 2 MiB (plain, T x 512)
    short* vt   = (short*)(ws + ((size_t)30 << 20));     // 2 MiB (plain V^T, 512 x T)
    short* wob  = (short*)(ws + ((size_t)32 << 20));     // 8 MiB
    short* ob   = xb;      // x dead after QKV GEMM

    conv_all<<<7168, 256, 0, stream>>>(x, Wq, Wk, Wv, Wo, xb, wqkv, wob);
    gemm8<128, 0><<<dim3(24, 16), 512, 0, stream>>>(xb, wqkv, qb, kb, vt, nullptr, nullptr);
    attn_fwd<<<512, 512, 0, stream>>>(qb, kb, vt, ob);
    gemm8<64, 1><<<dim3(32, 16), 512, 0, stream>>>(ob, wob, nullptr, nullptr, nullptr,
                                                   (float*)d_out, bo);
}

// Round 11
// 117.752 us; speedup vs baseline: 1.4213x; 1.4213x over previous
//
#include <hip/hip_runtime.h>
#include <hip/hip_bf16.h>

typedef __attribute__((ext_vector_type(8))) short short8;
typedef __attribute__((ext_vector_type(16))) float floatx16;
typedef __attribute__((ext_vector_type(4))) float floatx4;
typedef __attribute__((ext_vector_type(4))) unsigned uintx4;

__device__ __forceinline__ short f2bf(float f) {
    unsigned u = __builtin_bit_cast(unsigned, f);
    u += 0x7fffu + ((u >> 16) & 1u);   // RNE
    return (short)(u >> 16);
}

__device__ __forceinline__ unsigned pk_bf16(float lo, float hi) {
    unsigned short a = __builtin_bit_cast(unsigned short, (__bf16)lo);
    unsigned short b = __builtin_bit_cast(unsigned short, (__bf16)hi);
    return (unsigned)a | ((unsigned)b << 16);
}

__device__ __forceinline__ void gload_lds16(const void* g, void* l) {
    __builtin_amdgcn_global_load_lds(
        (const __attribute__((address_space(1))) unsigned*)g,
        (__attribute__((address_space(3))) unsigned*)l, 16, 0, 0);
}

// ---------------------------------------------------------------------------
// f32 -> bf16 convert for x, Wq/Wk/Wv, Wo — one launch. 64-col-tile XOR
// swizzle (GEMM operand layout): chunk cc of dest row holds src chunk cc^(row&7).
__global__ __launch_bounds__(256)
void conv_all(const float* __restrict__ x, const float* __restrict__ Wq,
              const float* __restrict__ Wk, const float* __restrict__ Wv,
              const float* __restrict__ Wo, short* __restrict__ xb,
              short* __restrict__ wqkv, short* __restrict__ wob) {
    const int bid = blockIdx.x;                // 0..7167
    const float* src; short* dst; int srow, drow;
    if (bid < 2048)      { src = x;  dst = xb;  srow = bid;        drow = bid; }
    else if (bid < 5120) {
        int r = bid - 2048;
        dst = wqkv; drow = r;
        if (r < 2048)      { src = Wq; srow = r; }
        else if (r < 2560) { src = Wk; srow = r - 2048; }
        else               { src = Wv; srow = r - 2560; }
    } else               { src = Wo; dst = wob; srow = bid - 5120; drow = srow; }
    const int c = threadIdx.x;
    const int kt = c >> 3, cc = c & 7;
    const float* s = src + (size_t)srow * 2048 + kt * 64 + (cc ^ (drow & 7)) * 8;
    float4 v0 = *(const float4*)s;
    float4 v1 = *(const float4*)(s + 4);
    short8 o = { f2bf(v0.x), f2bf(v0.y), f2bf(v0.z), f2bf(v0.w),
                 f2bf(v1.x), f2bf(v1.y), f2bf(v1.z), f2bf(v1.w) };
    *(short8*)(dst + (size_t)drow * 2048 + kt * 64 + cc * 8) = o;
}

// ---------------------------------------------------------------------------
// 8-wave double-buffered bf16 GEMM (round-8 proven structure).
// EPI 0: QKV epilogue (qb pre-scaled; kb/vt attn-swizzled). EPI 1: f32 + bias.
template<int BN, int EPI>
__global__ __launch_bounds__(512, 4)
void gemm8(const short* __restrict__ A, const short* __restrict__ Bw,
           short* __restrict__ qb, short* __restrict__ kb, short* __restrict__ vt,
           float* __restrict__ fout, const float* __restrict__ bias) {
    constexpr int K = 2048;
    constexpr int NN = BN / 32;
    constexpr int ACH = 128 * 8;
    constexpr int NCH = (128 + BN) * 8;
    constexpr int NIT = K / 64;
    __shared__ short sm[2][(128 + BN) * 64];

    const int t = threadIdx.x, lane = t & 63, w = t >> 6;
    const int wm = w & 3, wn = w >> 2;
    const int l15 = lane & 15, lh = lane >> 4;
    const int bn = blockIdx.x, bm = blockIdx.y;
    const int ra0 = bm * 128;
    const short* Bbase = Bw + (size_t)bn * BN * K;

    floatx4 acc[2][NN] = {};

    auto stage = [&](int buf, int k0) {
        short* base = &sm[buf][0];
        #pragma unroll
        for (int i = 0; i < NCH / 512; ++i) {
            int c = i * 512 + t;
            if (c < ACH) {
                int row = c >> 3, cc = c & 7;
                gload_lds16(A + (size_t)(ra0 + row) * K + k0 + cc * 8, base + c * 8);
            } else {
                int c2 = c - ACH;
                int row = c2 >> 3, cc = c2 & 7;
                gload_lds16(Bbase + (size_t)row * K + k0 + cc * 8, base + (ACH + c2) * 8);
            }
        }
    };

    stage(0, 0);
    #pragma unroll 1
    for (int it = 0; it < NIT; ++it) {
        __syncthreads();                       // slab `it` ready
        if (it + 1 < NIT) stage((it + 1) & 1, (it + 1) * 64);
        const short* As = &sm[it & 1][0];
        const short* Bs = As + 128 * 64;
        #pragma unroll
        for (int kf = 0; kf < 2; ++kf) {
            short8 a[2], b[NN];
            #pragma unroll
            for (int m = 0; m < 2; ++m) {
                int arow = wm * 32 + m * 16 + l15;
                a[m] = *(const short8*)(As + arow * 64 + (((kf * 4 + lh) ^ (arow & 7)) << 3));
            }
            #pragma unroll
            for (int n = 0; n < NN; ++n) {
                int brow = wn * (BN / 2) + n * 16 + l15;
                b[n] = *(const short8*)(Bs + brow * 64 + (((kf * 4 + lh) ^ (brow & 7)) << 3));
            }
            #pragma unroll
            for (int m = 0; m < 2; ++m)
                #pragma unroll
                for (int n = 0; n < NN; ++n)
                    acc[m][n] = __builtin_amdgcn_mfma_f32_16x16x32_bf16(a[m], b[n], acc[m][n], 0, 0, 0);
        }
    }

    #pragma unroll
    for (int m = 0; m < 2; ++m) {
        #pragma unroll
        for (int n = 0; n < NN; ++n) {
            #pragma unroll
            for (int r = 0; r < 4; ++r) {
                int row = ra0 + wm * 32 + m * 16 + lh * 4 + r;
                int col = bn * BN + wn * (BN / 2) + n * 16 + l15;
                float v = acc[m][n][r];
                if constexpr (EPI == 1) {
                    fout[(size_t)row * 2048 + col] = v + bias[col];
                } else {
                    if (col < 2048) {
                        qb[(size_t)row * 2048 + col] = f2bf(v * 0.18033688011112042f);
                    } else if (col < 2560) {
                        int kcol = col - 2048, within = kcol & 63;
                        int cp = ((within >> 3) ^ (row & 7)) & 7;
                        kb[(size_t)row * 512 + (kcol & ~63) + (cp << 3) + (within & 7)] = f2bf(v);
                    } else {
                        int dg = col - 2560;
                        int cp = (((row >> 3) & 7) ^ (dg & 7)) & 7;
                        vt[(size_t)dg * 2048 + (row & ~63) + (cp << 3) + (row & 7)] = f2bf(v);
                    }
                }
            }
        }
    }
}

// ---------------------------------------------------------------------------
// Causal GQA attention (round-6 proven structure): 8 waves = 4 q-strips
// {A0,A1,B0,B1} x kv-parity; pair {i, 31-i}; 128-kv-row slabs double-buffered;
// one barrier per slab; parity partials merged per-strip via LDS.
// NEW: grid (32,16) with hq = blockIdx.x -> linear id % 8 == hq % 8, so each
// XCD serves 4 heads = 2 MB KV (L2-resident) instead of all 32 heads (4 MB).
__global__ __launch_bounds__(512, 4)
void attn_fwd(const short* __restrict__ qb, const short* __restrict__ kb,
              const short* __restrict__ vt, short* __restrict__ ob) {
    __shared__ __align__(16) short smem[2][16384];  // per buf: K 128x64 | V^T 64x128

    const int t = threadIdx.x, lane = t & 63, w = t >> 6;
    const int l31 = lane & 31, hi = lane >> 5;
    const int hq = blockIdx.x, hk = hq >> 2;   // XCD-local head placement
    const int pairi = blockIdx.y;              // 0..15
    const int qtA = pairi, qtB = 31 - pairi;
    const int a = w >> 1, p = w & 1;           // strip 0..3, kv parity
    const int s = a & 1;
    const int myqt = (a < 2) ? qtA : qtB;
    const int q0 = myqt * 64 + s * 32;
    const int rg = q0 + l31;                   // this lane's q row
    const int swl = l31 & 7;

    short8 qf[4];
    {
        const short* qrow = qb + (size_t)rg * 2048 + hq * 64;
        #pragma unroll
        for (int kk = 0; kk < 4; ++kk)
            qf[kk] = *(const short8*)(qrow + kk * 16 + hi * 8);
    }

    float m = -3e38f, l = 0.f;
    floatx16 acc[2] = {};

    auto stage = [&](int buf, int j0) {        // j0 = slab base kv-row
        short* base = &smem[buf][0];
        #pragma unroll
        for (int i = 0; i < 4; ++i) {
            int c = i * 512 + t;
            if (i < 2) {                       // K chunks 0..1023
                int row = c >> 3, cc = c & 7;
                gload_lds16(kb + (size_t)(j0 + row) * 512 + hk * 64 + cc * 8, base + c * 8);
            } else {                           // V chunks 1024..2047
                int cv = c - 1024, drow = cv >> 4, cc = cv & 15;
                gload_lds16(vt + (size_t)(hk * 64 + drow) * 2048 + j0 + cc * 8, base + c * 8);
            }
        }
    };

    const int nss = (qtB >> 1) + 1;
    stage(0, 0);
    #pragma unroll 1
    for (int ss = 0; ss < nss; ++ss) {
        __syncthreads();                       // slab ss ready
        if (ss + 1 < nss) stage((ss + 1) & 1, (ss + 1) * 128);
        const int kt = 2 * ss + p;
        if (kt <= myqt) {
            const short* K0 = &smem[ss & 1][0];
            const short* V0 = &smem[ss & 1][8192];

            // ---- S^T = K . Q^T (2 kv-blocks x 4 k-steps)
            floatx16 sT[2];
            #pragma unroll
            for (int kb2 = 0; kb2 < 2; ++kb2) {
                floatx16 acc2 = {};
                const int row = p * 64 + kb2 * 32 + l31;
                #pragma unroll
                for (int kk = 0; kk < 4; ++kk) {
                    short8 kf = *(const short8*)(K0 + row * 64 + (((2 * kk + hi) ^ swl) << 3));
                    acc2 = __builtin_amdgcn_mfma_f32_32x32x16_bf16(kf, qf[kk], acc2, 0, 0, 0);
                }
                sT[kb2] = acc2;
            }

            // ---- causal mask (diagonal tile only)
            if (kt == myqt) {
                #pragma unroll
                for (int kb2 = 0; kb2 < 2; ++kb2)
                    #pragma unroll
                    for (int r = 0; r < 16; ++r) {
                        int jg = kt * 64 + kb2 * 32 + (r & 3) + 8 * (r >> 2) + 4 * hi;
                        if (jg > rg) sT[kb2][r] = -3e38f;
                    }
            }

            // ---- row max
            float v[16];
            #pragma unroll
            for (int r = 0; r < 16; ++r) v[r] = fmaxf(sT[0][r], sT[1][r]);
            #pragma unroll
            for (int st = 8; st >= 1; st >>= 1)
                #pragma unroll
                for (int r = 0; r < 8; ++r)
                    if (r < st) v[r] = fmaxf(v[r], v[r + st]);
            float tm = fmaxf(v[0], __shfl_xor(v[0], 32));

            // ---- defer-max
            if (!__all(tm <= m + 8.0f)) {
                float mn = fmaxf(m, tm);
                float sf = __builtin_amdgcn_exp2f(m - mn);
                m = mn;
                l *= sf;
                #pragma unroll
                for (int n = 0; n < 2; ++n)
                    #pragma unroll
                    for (int r = 0; r < 16; ++r) acc[n][r] *= sf;
            }

            // ---- p = exp2(s - m), row sum
            float sv[16];
            #pragma unroll
            for (int kb2 = 0; kb2 < 2; ++kb2)
                #pragma unroll
                for (int r = 0; r < 16; ++r)
                    sT[kb2][r] = __builtin_amdgcn_exp2f(sT[kb2][r] - m);
            #pragma unroll
            for (int r = 0; r < 16; ++r) sv[r] = sT[0][r] + sT[1][r];
            #pragma unroll
            for (int st = 8; st >= 1; st >>= 1)
                #pragma unroll
                for (int r = 0; r < 8; ++r)
                    if (r < st) sv[r] += sv[r + st];
            l += sv[0] + __shfl_xor(sv[0], 32);

            // ---- P^T -> B-fragments (cvt_pk + cross-half exchange), then PV
            #pragma unroll
            for (int kb2 = 0; kb2 < 2; ++kb2) {
                unsigned Qd[8], Pd[8];
                #pragma unroll
                for (int c = 0; c < 8; ++c)
                    Qd[c] = pk_bf16(sT[kb2][2 * c], sT[kb2][2 * c + 1]);
                #pragma unroll
                for (int c = 0; c < 8; ++c)
                    Pd[c] = __shfl_xor(Qd[c], 32);
                #pragma unroll
                for (int b = 0; b < 2; ++b) {
                    uintx4 j;
                    if (b == 0) {
                        j.x = hi ? Pd[2] : Qd[0];
                        j.y = hi ? Pd[3] : Qd[1];
                        j.z = hi ? Qd[2] : Pd[0];
                        j.w = hi ? Qd[3] : Pd[1];
                    } else {
                        j.x = hi ? Pd[6] : Qd[4];
                        j.y = hi ? Pd[7] : Qd[5];
                        j.z = hi ? Qd[6] : Pd[4];
                        j.w = hi ? Qd[7] : Pd[5];
                    }
                    short8 pf = __builtin_bit_cast(short8, j);
                    const int kk = kb2 * 2 + b;
                    const int ch = p * 64 + (((2 * kk + hi) ^ swl) << 3);
                    short8 vf0 = *(const short8*)(V0 + l31 * 128 + ch);
                    acc[0] = __builtin_amdgcn_mfma_f32_32x32x16_bf16(vf0, pf, acc[0], 0, 0, 0);
                    short8 vf1 = *(const short8*)(V0 + (32 + l31) * 128 + ch);
                    acc[1] = __builtin_amdgcn_mfma_f32_32x32x16_bf16(vf1, pf, acc[1], 0, 0, 0);
                }
            }
        }
    }

    // ---- merge the two kv-parity partials per strip (lane = q column)
    __syncthreads();                           // all compute done; reuse smem
    float* mb = (float*)&smem[0][0] + ((size_t)a * 64 + lane) * 34;
    if (p == 1) {
        #pragma unroll
        for (int n = 0; n < 2; ++n)
            #pragma unroll
            for (int r = 0; r < 16; ++r) mb[n * 16 + r] = acc[n][r];
        mb[32] = m;
        mb[33] = l;
    }
    __syncthreads();
    if (p == 0) {
        const float m1 = mb[32], l1 = mb[33];
        const float M = fmaxf(m, m1);
        const float sf0 = __builtin_amdgcn_exp2f(m - M);
        const float sf1 = __builtin_amdgcn_exp2f(m1 - M);
        const float linv = 1.0f / (sf0 * l + sf1 * l1);
        const int sw8 = rg & 7;
        #pragma unroll
        for (int n = 0; n < 2; ++n) {
            #pragma unroll
            for (int g = 0; g < 4; ++g) {
                #pragma unroll
                for (int e = 0; e < 4; e += 2) {
                    int r = 4 * g + e;
                    float o0 = (sf0 * acc[n][r]     + sf1 * mb[n * 16 + r])     * linv;
                    float o1 = (sf0 * acc[n][r + 1] + sf1 * mb[n * 16 + r + 1]) * linv;
                    unsigned pkv = pk_bf16(o0, o1);
                    int d = 32 * n + e + 8 * g + 4 * hi;
                    int col = hq * 64 + d;
                    int cp = ((col >> 3) & 7) ^ sw8;           // 64-col GEMM-A swizzle
                    *(unsigned*)(ob + (size_t)rg * 2048 + (col & ~63) + (cp << 3) + (col & 7)) = pkv;
                }
            }
        }
    }
}

// ---------------------------------------------------------------------------
extern "C" void kernel_launch(void* const* d_in, const int* in_sizes, int n_in,
                              void* d_out, int out_size, void* d_ws, size_t ws_size,
                              hipStream_t stream) {
    const float* x  = (const float*)d_in[0];
    const float* Wq = (const float*)d_in[1];
    const float* Wk = (const float*)d_in[2];
    const float* Wv = (const float*)d_in[3];
    const float* Wo = (const float*)d_in[4];
    const float* bo = (const float*)d_in[5];

    char* ws = (char*)d_ws;
    short* xb   = (short*)ws;                            // 8 MiB (reused as ob)
    short* wqkv = (short*)(ws + ((size_t)8  << 20));     // 12 MiB
    short* qb   = (short*)(ws + ((size_t)20 << 20));     // 8 MiB
    short* kb   = (short*)(ws + ((size_t)28 << 20));     // 2 MiB (attn-swizzled)
    short* vt   = (short*)(ws + ((size_t)30 << 20));     // 2 MiB (V^T, attn-swizzled)
    short* wob  = (short*)(ws + ((size_t)32 << 20));     // 8 MiB
    short* ob   = xb;      // x dead after QKV GEMM

    conv_all<<<7168, 256, 0, stream>>>(x, Wq, Wk, Wv, Wo, xb, wqkv, wob);
    gemm8<128, 0><<<dim3(24, 16), 512, 0, stream>>>(xb, wqkv, qb, kb, vt, nullptr, nullptr);
    attn_fwd<<<dim3(32, 16), 512, 0, stream>>>(qb, kb, vt, ob);
    gemm8<64, 1><<<dim3(32, 16), 512, 0, stream>>>(ob, wob, nullptr, nullptr, nullptr,
                                                   (float*)d_out, bo);
}